// Round 1
// 670.452 us; speedup vs baseline: 1.0134x; 1.0134x over previous
//
#include <hip/hip_runtime.h>

#define INVALID_TOKEN_ID -1

__device__ __forceinline__ void upd4(float4 v, int base, float& best, int& bestIdx) {
    // strictly increasing indices within a thread -> '>' keeps first occurrence
    if (v.x > best) { best = v.x; bestIdx = base; }
    if (v.y > best) { best = v.y; bestIdx = base + 1; }
    if (v.z > best) { best = v.z; bestIdx = base + 2; }
    if (v.w > best) { best = v.w; bestIdx = base + 3; }
}

// One block (512 thr = 8 waves) per token row: argmax over `vocab` fp32 logits.
// 4 blocks/CU * 8 waves = 32 waves/CU. 8 independent float4 load streams per
// thread (8 KB in flight per wave) to cover the HBM BW*latency product --
// the previous 2-stream version kept only ~2 MB in flight chip-wide and ran
// at ~1.5 TB/s (latency-bound). Streams are processed in increasing index
// order so first-occurrence tie-break (jnp.argmax) is preserved.
__global__ __launch_bounds__(512, 8) void rowargmax_kernel(
    const float* __restrict__ logits, int* __restrict__ amax, int vocab) {
    const int row = blockIdx.x;
    const int t = threadIdx.x;
    const float* rowp = logits + (size_t)row * (size_t)vocab;

    const int nvec = vocab >> 2;  // float4 count
    const float4* rowv = (const float4*)rowp;

    float best = -__builtin_inff();
    int idx = 0;

    int i = t;
    // main loop: 8 loads in flight per thread, chunk stride 4096 float4s (64 KB/block-iter)
    for (; i + 3584 < nvec; i += 4096) {
        float4 v0 = rowv[i];
        float4 v1 = rowv[i + 512];
        float4 v2 = rowv[i + 1024];
        float4 v3 = rowv[i + 1536];
        float4 v4 = rowv[i + 2048];
        float4 v5 = rowv[i + 2560];
        float4 v6 = rowv[i + 3072];
        float4 v7 = rowv[i + 3584];
        const int base = i << 2;
        upd4(v0, base, best, idx);
        upd4(v1, base + 2048, best, idx);
        upd4(v2, base + 4096, best, idx);
        upd4(v3, base + 6144, best, idx);
        upd4(v4, base + 8192, best, idx);
        upd4(v5, base + 10240, best, idx);
        upd4(v6, base + 12288, best, idx);
        upd4(v7, base + 14336, best, idx);
    }
    // remainder: 2-stream then 1-stream (same structure as before)
    for (; i + 512 < nvec; i += 1024) {
        float4 a = rowv[i];
        float4 b = rowv[i + 512];
        upd4(a, i << 2, best, idx);
        upd4(b, (i + 512) << 2, best, idx);
    }
    if (i < nvec) {
        float4 a = rowv[i];
        upd4(a, i << 2, best, idx);
    }
    // scalar tail (vocab not divisible by 4); tail indices exceed vector ones
    for (int j = (nvec << 2) + t; j < vocab; j += 512) {
        float v = rowp[j];
        if (v > best) { best = v; idx = j; }
    }

    // wave (64-lane) butterfly reduction; ties -> lower index
    #pragma unroll
    for (int off = 32; off > 0; off >>= 1) {
        float ov = __shfl_down(best, off, 64);
        int oi = __shfl_down(idx, off, 64);
        if (ov > best || (ov == best && oi < idx)) { best = ov; idx = oi; }
    }

    __shared__ float svals[8];
    __shared__ int sidx[8];
    const int wave = t >> 6;
    if ((t & 63) == 0) { svals[wave] = best; sidx[wave] = idx; }
    __syncthreads();
    if (t == 0) {
        #pragma unroll
        for (int w = 1; w < 8; ++w) {
            if (svals[w] > best || (svals[w] == best && sidx[w] < idx)) {
                best = svals[w]; idx = sidx[w];
            }
        }
        amax[row] = idx;
    }
}

// One thread per batch row: cumulative accept + bonus position.
__global__ void finalize_kernel(const int* __restrict__ amax,
                                const int* __restrict__ spec,
                                int* __restrict__ out, int B, int k) {
    int b = blockIdx.x * blockDim.x + threadIdx.x;
    if (b >= B) return;
    const int kp1 = k + 1;

    int outv[8];
    int gen[8];
    #pragma unroll
    for (int j = 0; j < 8; ++j) { outv[j] = 0; gen[j] = 0; }

    for (int j = 0; j < kp1; ++j) outv[j] = amax[b * kp1 + j];

    int acc = 1;
    int firstZero = k;  // if all k drafts accepted, bonus at position k
    for (int j = 0; j < k; ++j) {
        if (acc && outv[j] != spec[b * k + j]) { acc = 0; firstZero = j; }
        gen[j] = acc;
    }
    gen[k] = 0;
    gen[firstZero] = 1;  // first rejected / bonus position

    for (int j = 0; j < kp1; ++j)
        out[b * kp1 + j] = gen[j] ? outv[j] : INVALID_TOKEN_ID;
}

extern "C" void kernel_launch(void* const* d_in, const int* in_sizes, int n_in,
                              void* d_out, int out_size, void* d_ws, size_t ws_size,
                              hipStream_t stream) {
    const float* logits = (const float*)d_in[0];
    const int* spec = (const int*)d_in[1];
    int* out = (int*)d_out;

    const int total_tokens = out_size;                 // B*(k+1) = 1024
    const int vocab = in_sizes[0] / total_tokens;      // 128000
    const int B = out_size - in_sizes[1];              // B*(k+1) - B*k = 128
    const int k = in_sizes[1] / B;                     // 7

    int* amax = (int*)d_ws;  // total_tokens ints of scratch

    rowargmax_kernel<<<total_tokens, 512, 0, stream>>>(logits, amax, vocab);
    finalize_kernel<<<(B + 127) / 128, 128, 0, stream>>>(amax, spec, out, B, k);
}

// Round 2
// 636.182 us; speedup vs baseline: 1.0679x; 1.0539x over previous
//
#include <hip/hip_runtime.h>

#define INVALID_TOKEN_ID -1

typedef float f32x4 __attribute__((ext_vector_type(4)));

__device__ __forceinline__ void upd4(f32x4 v, int base, float& best, int& bestIdx) {
    // strictly increasing indices within a thread -> '>' keeps first occurrence
    if (v[0] > best) { best = v[0]; bestIdx = base; }
    if (v[1] > best) { best = v[1]; bestIdx = base + 1; }
    if (v[2] > best) { best = v[2]; bestIdx = base + 2; }
    if (v[3] > best) { best = v[3]; bestIdx = base + 3; }
}

// SEGS blocks per row, 256 threads each. Each block argmaxes a contiguous
// ~128 KB segment of one row and writes a (val, idx) partial to workspace.
//   - 256-thr blocks + (256,4) bounds: 128-VGPR budget so the 4 load streams
//     stay genuinely in flight (the old (512,8)=64-VGPR cap forced register
//     reuse and serialized the streams -> stream depth was a no-op).
//   - nontemporal loads: the harness's 2 GB workspace poison runs right
//     before us, so L2/L3 are full of dirty lines; NT reads skip allocation
//     and avoid the dirty-evict-then-fetch serialization. Zero reuse anyway.
__global__ __launch_bounds__(256, 4) void rowargmax_part(
    const float* __restrict__ logits, float* __restrict__ pval,
    int* __restrict__ pidx, int vocab, int segs) {
    const int row = blockIdx.x / segs;
    const int seg = blockIdx.x - row * segs;
    const int t = threadIdx.x;

    const float* rowp = logits + (size_t)row * (size_t)vocab;
    const f32x4* rowv = (const f32x4*)rowp;
    const int nvec = vocab >> 2;
    const int segLen = (nvec + segs - 1) / segs;
    const int begin = seg * segLen;
    const int end = min(begin + segLen, nvec);

    float best = -__builtin_inff();
    int idx = 0;

    int i = begin + t;
    // 4 independent streams, 16 KB apart per block-iter; increasing index order
    for (; i + 768 < end; i += 1024) {
        f32x4 a = __builtin_nontemporal_load(&rowv[i]);
        f32x4 b = __builtin_nontemporal_load(&rowv[i + 256]);
        f32x4 c = __builtin_nontemporal_load(&rowv[i + 512]);
        f32x4 d = __builtin_nontemporal_load(&rowv[i + 768]);
        upd4(a, i << 2, best, idx);
        upd4(b, (i + 256) << 2, best, idx);
        upd4(c, (i + 512) << 2, best, idx);
        upd4(d, (i + 768) << 2, best, idx);
    }
    for (; i < end; i += 256) {
        f32x4 a = __builtin_nontemporal_load(&rowv[i]);
        upd4(a, i << 2, best, idx);
    }
    // scalar tail (vocab % 4) belongs to the last segment; tail idx > all vector idx
    if (seg == segs - 1) {
        for (int j = (nvec << 2) + t; j < vocab; j += 256) {
            float v = rowp[j];
            if (v > best) { best = v; idx = j; }
        }
    }

    // wave (64-lane) butterfly reduction; ties -> lower index
    #pragma unroll
    for (int off = 32; off > 0; off >>= 1) {
        float ov = __shfl_down(best, off, 64);
        int oi = __shfl_down(idx, off, 64);
        if (ov > best || (ov == best && oi < idx)) { best = ov; idx = oi; }
    }

    __shared__ float svals[4];
    __shared__ int sidx[4];
    const int wave = t >> 6;
    if ((t & 63) == 0) { svals[wave] = best; sidx[wave] = idx; }
    __syncthreads();
    if (t == 0) {
        #pragma unroll
        for (int w = 1; w < 4; ++w) {
            if (svals[w] > best || (svals[w] == best && sidx[w] < idx)) {
                best = svals[w]; idx = sidx[w];
            }
        }
        const int p = row * segs + seg;
        pval[p] = best;
        pidx[p] = idx;
    }
}

// One thread per batch row: merge segment partials (in segment order ->
// first-occurrence tie-break preserved), then cumulative accept + bonus.
__global__ void finalize_kernel(const float* __restrict__ pval,
                                const int* __restrict__ pidx,
                                const int* __restrict__ spec,
                                int* __restrict__ out, int B, int k, int segs) {
    int b = blockIdx.x * blockDim.x + threadIdx.x;
    if (b >= B) return;
    const int kp1 = k + 1;

    int outv[8];
    int gen[8];
    #pragma unroll
    for (int j = 0; j < 8; ++j) { outv[j] = 0; gen[j] = 0; }

    for (int j = 0; j < kp1; ++j) {
        const int tok = b * kp1 + j;
        float bv = pval[tok * segs];
        int bi = pidx[tok * segs];
        for (int s = 1; s < segs; ++s) {
            float v = pval[tok * segs + s];
            int ix = pidx[tok * segs + s];
            if (v > bv || (v == bv && ix < bi)) { bv = v; bi = ix; }
        }
        outv[j] = bi;
    }

    int acc = 1;
    int firstZero = k;  // if all k drafts accepted, bonus at position k
    for (int j = 0; j < k; ++j) {
        if (acc && outv[j] != spec[b * k + j]) { acc = 0; firstZero = j; }
        gen[j] = acc;
    }
    gen[k] = 0;
    gen[firstZero] = 1;  // first rejected / bonus position

    for (int j = 0; j < kp1; ++j)
        out[b * kp1 + j] = gen[j] ? outv[j] : INVALID_TOKEN_ID;
}

extern "C" void kernel_launch(void* const* d_in, const int* in_sizes, int n_in,
                              void* d_out, int out_size, void* d_ws, size_t ws_size,
                              hipStream_t stream) {
    const float* logits = (const float*)d_in[0];
    const int* spec = (const int*)d_in[1];
    int* out = (int*)d_out;

    const int total_tokens = out_size;                 // B*(k+1) = 1024
    const int vocab = in_sizes[0] / total_tokens;      // 128000
    const int B = out_size - in_sizes[1];              // B*(k+1) - B*k = 128
    const int k = in_sizes[1] / B;                     // 7

    const int SEGS = 4;  // blocks per row; each streams a contiguous ~128 KB
    float* pval = (float*)d_ws;                        // total_tokens*SEGS floats
    int* pidx = (int*)(pval + total_tokens * SEGS);    // total_tokens*SEGS ints

    rowargmax_part<<<total_tokens * SEGS, 256, 0, stream>>>(logits, pval, pidx, vocab, SEGS);
    finalize_kernel<<<(B + 127) / 128, 128, 0, stream>>>(pval, pidx, spec, out, B, k, SEGS);
}